// Round 8
// baseline (94.607 us; speedup 1.0000x reference)
//
#include <hip/hip_runtime.h>
#include <hip/hip_fp16.h>

// Table-batched INT8 embedding-bag (SUM pooling) with per-row scale/bias dequant.
// T=4, E=1e6, D=64, B=8192, L=50 (ragged-safe).
#define T_TABLES 4
#define E_ROWS   1000000
#define D_DIM    64
#define B_BAGS   8192

typedef int   v4i __attribute__((ext_vector_type(4)));
typedef float v4f __attribute__((ext_vector_type(4)));

// Pass 1: pack per-row (scale, bias) into ONE half2 (4 B) per row.
// Vectorized: 4 rows/thread via float4 loads + one 16 B store (48 MB total,
// BW floor ~7.6 us). nt on the streamed f32 inputs; pk store temporal (reused
// by the main kernel's scattered gather).
__global__ __launch_bounds__(256)
void pack_params_kernel(const v4f* __restrict__ sc4,
                        const v4f* __restrict__ bs4,
                        v4i*       __restrict__ pk4,   // [T*E/4] of 4x half2
                        int n4)
{
    int i = blockIdx.x * 256 + threadIdx.x;
    const int stride = gridDim.x * 256;
    for (; i < n4; i += stride) {
        v4f s = __builtin_nontemporal_load(sc4 + i);
        v4f b = __builtin_nontemporal_load(bs4 + i);
        __half2 h0 = __floats2half2_rn(s[0], b[0]);
        __half2 h1 = __floats2half2_rn(s[1], b[1]);
        __half2 h2 = __floats2half2_rn(s[2], b[2]);
        __half2 h3 = __floats2half2_rn(s[3], b[3]);
        v4i o;
        o[0] = *reinterpret_cast<const int*>(&h0);
        o[1] = *reinterpret_cast<const int*>(&h1);
        o[2] = *reinterpret_cast<const int*>(&h2);
        o[3] = *reinterpret_cast<const int*>(&h3);
        pk4[i] = o;
    }
}

// Main kernel: UNCHANGED from R7 (clean A/B on the pack kernel).
// One block = 4 waves = 4 bags of the SAME table; table pinned to an XCD pair
// via bid&7. Lane l covers dim-group c=l&15 (dims 4c..4c+3) of row-slot g=l>>4:
// one int4 load/lane = 4 rows/instr (1 KiB). Rows TEMPORAL (L3 serves ~18%
// duplicate lookups, R7: -10 us); idx/out streamed nt.
__global__ __launch_bounds__(256, 8)
void tbe_fwd_kernel(const int*     __restrict__ qw,     // [T*E*D] int32 holding uint8
                    const __half2* __restrict__ pk,     // [T*E] packed (scale, bias)
                    const int*     __restrict__ idx,    // [T*B*L]
                    const int*     __restrict__ offs,   // [T*B+1]
                    float*         __restrict__ out)    // [B, T*D] float32
{
    const int lane = threadIdx.x & 63;
    const int w    = threadIdx.x >> 6;                 // wave id -> bag-in-quad
    const int bid  = blockIdx.x;                       // [0, 8192)
    const int t    = (bid & 7) >> 1;                   // table, pinned to XCD pair
    const int q    = ((bid >> 3) << 1) | (bid & 1);    // quad index [0, 2048)
    const int b    = q * 4 + w;                        // bag within table [0, 8192)
    const int g    = lane >> 4;                        // row-slot within 4-row group
    const int c    = lane & 15;                        // dim-group (4 dims)

    const int bag  = t * B_BAGS + b;
    const int off0 = offs[bag];
    const int off1 = offs[bag + 1];

    const unsigned tE = (unsigned)t * (unsigned)E_ROWS;
    const int* __restrict__ qbase = qw + (size_t)tE * D_DIM;

    float ax = 0.f, ay = 0.f, az = 0.f, aw = 0.f;  // partial dims 4c..4c+3
    float bsum = 0.f;                               // per-lane bias partial

    for (int base = off0; base < off1; base += 64) {
        const int n = min(64, off1 - base);

        int   myidx = 0;
        float ms    = 0.f;
        if (lane < n) {
            myidx = __builtin_nontemporal_load(idx + base + lane);  // streamed once
            float2 p = __half22float2(pk[tE + (unsigned)myidx]);    // cached gather
            ms    = p.x;
            bsum += p.y;
        }

        // 4 rows per body; up to 4 bodies in flight -> 4 KiB per wave.
        // Row-slots rl >= n contribute 0 (ms==0 via the lane<n guard).
        #define BODY(J) {                                                         \
            const int   rl = (J) + g;                                             \
            const int   r  = __shfl(myidx, rl, 64);                               \
            const float s  = __shfl(ms,    rl, 64);                               \
            const v4i   qv = *reinterpret_cast<const v4i*>(                       \
                    qbase + (((size_t)(unsigned)r) << 6) + (c << 2));             \
            ax = fmaf((float)qv[0], s, ax);                                       \
            ay = fmaf((float)qv[1], s, ay);                                       \
            az = fmaf((float)qv[2], s, az);                                       \
            aw = fmaf((float)qv[3], s, aw); }

        int j = 0;
        for (; j + 16 <= n; j += 16) { BODY(j) BODY(j + 4) BODY(j + 8) BODY(j + 12) }
        for (; j < n; j += 4)        { BODY(j) }   // tail: <=3 dummy row-slots
        #undef BODY
    }

    // Reduce the 4 row-slot partials (lanes differing in bits 4..5).
    #pragma unroll
    for (int o = 16; o <= 32; o <<= 1) {
        ax += __shfl_xor(ax, o, 64);
        ay += __shfl_xor(ay, o, 64);
        az += __shfl_xor(az, o, 64);
        aw += __shfl_xor(aw, o, 64);
    }
    // Bias sum across the whole wave; added uniformly to every dim.
    #pragma unroll
    for (int o = 32; o > 0; o >>= 1) bsum += __shfl_xor(bsum, o, 64);

    if (lane < 16) {
        v4f r = { ax + bsum, ay + bsum, az + bsum, aw + bsum };
        __builtin_nontemporal_store(r,
            reinterpret_cast<v4f*>(out + (size_t)b * (T_TABLES * D_DIM)
                                       + t * D_DIM + (c << 2)));
    }
}

extern "C" void kernel_launch(void* const* d_in, const int* in_sizes, int n_in,
                              void* d_out, int out_size, void* d_ws, size_t ws_size,
                              hipStream_t stream)
{
    const int*   qw   = (const int*)  d_in[0];
    const float* sc   = (const float*)d_in[1];
    const float* bs   = (const float*)d_in[2];
    const int*   idx  = (const int*)  d_in[3];
    const int*   offs = (const int*)  d_in[4];
    float*       out  = (float*)      d_out;

    __half2* pk = (__half2*)d_ws;   // 4M * 4 B = 16 MB << ws_size

    const int n4 = (T_TABLES * E_ROWS) / 4;   // 1M float4 groups
    hipLaunchKernelGGL(pack_params_kernel, dim3(1024), dim3(256), 0, stream,
                       (const v4f*)sc, (const v4f*)bs, (v4i*)pk, n4);

    hipLaunchKernelGGL(tbe_fwd_kernel, dim3(8192), dim3(256), 0, stream,
                       qw, pk, idx, offs, out);
}